// Round 1
// baseline (2341.082 us; speedup 1.0000x reference)
//
#include <hip/hip_runtime.h>
#include <hip/hip_fp16.h>

#define Hn 128
#define Wn 128
#define HWn 16384
#define Cn 64
#define Bn 8
#define NTOT (Bn*Cn*HWn)   /* 8388608 */
#define NPIX (Bn*HWn)      /* 131072  */
#define DTc 0.3f
#define EPSc 1e-5f

__device__ __forceinline__ float sigm(float t){ return 1.0f/(1.0f+__expf(-t)); }
__device__ __forceinline__ float ldx(const float* __restrict__ p){ return *p; }
__device__ __forceinline__ float ldx(const __half* __restrict__ p){ return __half2float(*p); }
__device__ __forceinline__ void stx(float* __restrict__ p, float v){ *p = v; }
__device__ __forceinline__ void stx(__half* __restrict__ p, float v){ *p = __float2half(v); }

// ---------------- prep: style constant + weight transposes ----------------
__global__ void prep(const float* __restrict__ style, const float* __restrict__ w1,
                     const float* __restrict__ b1, const float* __restrict__ pw,
                     const float* __restrict__ pw1, float* __restrict__ w1T,
                     float* __restrict__ c1, float* __restrict__ pwT,
                     float* __restrict__ pw1T)
{
    int t = threadIdx.x;
    if (t < 32) {
        float s = b1[t];
        for (int k = 0; k < 64; k++) s += w1[t*128 + 64 + k] * style[k];
        c1[t] = s;
    }
    for (int i = t; i < 2048; i += 256) { int c = i >> 5, j = i & 31; w1T[i] = w1[j*128 + c]; }
    for (int i = t; i < 4096; i += 256) {
        int c = i >> 6, k = i & 63;
        pwT[i]  = pw[k*64 + c];
        pw1T[i] = pw1[k*64 + c];
    }
}

// ---------------- hyper encoder: per pixel, outputs A=2*zeta*omega, B2=omega^2, gamma, beta (fp16) ----------------
__global__ void hyper(const float* __restrict__ force, const float* __restrict__ illum,
                      const float* __restrict__ w1T, const float* __restrict__ c1,
                      const float* __restrict__ w2, const float* __restrict__ b2,
                      const float* __restrict__ w3, const float* __restrict__ b3,
                      __half* __restrict__ Ah, __half* __restrict__ B2h,
                      __half* __restrict__ Gh, __half* __restrict__ Beh)
{
    int p = blockIdx.x * blockDim.x + threadIdx.x;
    if (p >= NPIX) return;
    int b  = p >> 14;
    int sp = p & (HWn - 1);
    int base = b * Cn * HWn + sp;

    float u1[32];
#pragma unroll
    for (int j = 0; j < 32; j++) u1[j] = c1[j];
    for (int c = 0; c < 64; c++) {
        float fc = force[base + c*HWn] + 0.2f * illum[base + c*HWn];
        const float* __restrict__ wr = w1T + c*32;
#pragma unroll
        for (int j = 0; j < 32; j++) u1[j] += wr[j] * fc;
    }
#pragma unroll
    for (int j = 0; j < 32; j++) { float v = u1[j]; u1[j] = v > 0.f ? v : 0.2f*v; }

    float u2[32];
#pragma unroll
    for (int i = 0; i < 32; i++) {
        float s = b2[i];
#pragma unroll
        for (int j = 0; j < 32; j++) s += w2[i*32 + j] * u1[j];
        u2[i] = s > 0.f ? s : 0.2f*s;
    }

    // groups 0 (omega) and 1 (zeta) -> A, B2
    for (int j = 0; j < 64; j++) {
        const float* __restrict__ r0 = w3 + j*32;
        const float* __restrict__ r1 = w3 + (64 + j)*32;
        float pwv = b3[j], pz = b3[64 + j];
#pragma unroll
        for (int i = 0; i < 32; i++) { pwv += r0[i]*u2[i]; pz += r1[i]*u2[i]; }
        float om = 2.0f * sigm(pwv);
        float ze = sigm(pz);
        Ah [base + j*HWn] = __float2half(2.0f * ze * om);
        B2h[base + j*HWn] = __float2half(om * om);
    }
    // groups 2 (gamma), 3 (beta)
    for (int j = 0; j < 64; j++) {
        const float* __restrict__ r2 = w3 + (128 + j)*32;
        const float* __restrict__ r3 = w3 + (192 + j)*32;
        float pg = b3[128 + j], pb = b3[192 + j];
#pragma unroll
        for (int i = 0; i < 32; i++) { pg += r2[i]*u2[i]; pb += r3[i]*u2[i]; }
        Gh [base + j*HWn] = __float2half(2.0f * sigm(pg));
        Beh[base + j*HWn] = __float2half(tanhf(pb));
    }
}

// ---------------- one symplectic-Euler oscillator step ----------------
template <typename Tin, typename Tout>
__global__ void osc_step(const Tin* __restrict__ Xin, Tout* __restrict__ Xout,
                         float* __restrict__ V,
                         const float* __restrict__ force, const float* __restrict__ illum,
                         const __half* __restrict__ Ah, const __half* __restrict__ B2h,
                         const float* __restrict__ dwk, const float* __restrict__ pwT)
{
    int p = blockIdx.x * blockDim.x + threadIdx.x;
    if (p >= NPIX) return;
    int b  = p >> 14;
    int sp = p & (HWn - 1);
    int y = sp >> 7, x = sp & 127;
    int base = b * Cn * HWn + sp;

    // pointwise coupling: acc[k] = sum_c pw[k][c] * x[c]
    float acc[64];
#pragma unroll
    for (int k = 0; k < 64; k++) acc[k] = 0.f;
#pragma unroll 2
    for (int c = 0; c < 64; c++) {
        float xc = ldx(Xin + base + c*HWn);
        const float* __restrict__ wr = pwT + c*64;
#pragma unroll
        for (int k = 0; k < 64; k++) acc[k] += wr[k] * xc;
    }

    // 3x3 tap masks/offsets (zero 'SAME' padding)
    int   yo[3] = { y > 0 ? -Wn : 0, 0, y < Hn-1 ? Wn : 0 };
    int   xo[3] = { x > 0 ? -1  : 0, 0, x < Wn-1 ? 1  : 0 };
    float my[3] = { y > 0 ? 1.f : 0.f, 1.f, y < Hn-1 ? 1.f : 0.f };
    float mx[3] = { x > 0 ? 1.f : 0.f, 1.f, x < Wn-1 ? 1.f : 0.f };
    float mm[9]; int oo[9];
#pragma unroll
    for (int dy = 0; dy < 3; dy++)
#pragma unroll
        for (int dx = 0; dx < 3; dx++) { mm[dy*3+dx] = my[dy]*mx[dx]; oo[dy*3+dx] = yo[dy]+xo[dx]; }

#pragma unroll
    for (int c = 0; c < 64; c++) {
        int cb = base + c*HWn;
        float xc = ldx(Xin + cb);
        float dws = 0.f;
#pragma unroll
        for (int t = 0; t < 9; t++) {
            float v = ldx(Xin + cb + oo[t]);
            dws += (dwk[c*9 + t] * mm[t]) * v;
        }
        float fc = force[cb] + 0.2f * illum[cb];
        float vv = V[cb];
        float accel = fc + acc[c] + dws - __half2float(Ah[cb]) * vv - __half2float(B2h[cb]) * xc;
        vv += accel * DTc;
        V[cb] = vv;
        stx(Xout + cb, xc + vv * DTc);
    }
}

// ---------------- instance norm stats ----------------
__global__ void inorm_stats(const float* __restrict__ force, const float* __restrict__ illum,
                            const float* __restrict__ X, float* __restrict__ mu,
                            float* __restrict__ rs)
{
    int bc = blockIdx.x;             // 0..511
    int base = bc * HWn;
    float s = 0.f, s2 = 0.f;
    for (int i = threadIdx.x; i < HWn; i += blockDim.x) {
        float v = force[base + i] + 0.2f * illum[base + i] + X[base + i];
        s += v; s2 += v*v;
    }
#pragma unroll
    for (int o = 32; o > 0; o >>= 1) { s += __shfl_down(s, o); s2 += __shfl_down(s2, o); }
    __shared__ float sh[16];
    int w = threadIdx.x >> 6, l = threadIdx.x & 63;
    if (l == 0) { sh[w] = s; sh[8 + w] = s2; }
    __syncthreads();
    if (threadIdx.x == 0) {
        float S = 0.f, S2 = 0.f;
        for (int i = 0; i < 4; i++) { S += sh[i]; S2 += sh[8 + i]; }
        float m = S / (float)HWn;
        float var = S2 / (float)HWn - m*m;
        mu[bc] = m;
        rs[bc] = rsqrtf(var + EPSc);
    }
}

// ---------------- instance norm apply + style modulation -> out_pre (fp16) ----------------
__global__ void modulate(const float* __restrict__ force, const float* __restrict__ illum,
                         const float* __restrict__ X, const __half* __restrict__ Gh,
                         const __half* __restrict__ Beh, const float* __restrict__ mu,
                         const float* __restrict__ rs, __half* __restrict__ outp)
{
    int e = blockIdx.x * blockDim.x + threadIdx.x;
    if (e >= NTOT) return;
    int bc = e >> 14;
    float fx = force[e] + 0.2f * illum[e] + X[e];
    float v = __half2float(Gh[e]) * ((fx - mu[bc]) * rs[bc]) + __half2float(Beh[e]);
    outp[e] = __float2half(v);
}

// ---------------- refine branch + layer scale -> final out ----------------
__global__ void refine(const __half* __restrict__ outp,
                       const float* __restrict__ rdwk, const float* __restrict__ rdwb,
                       const float* __restrict__ pw1T, const float* __restrict__ pb1,
                       const float* __restrict__ pw2, const float* __restrict__ pb2,
                       const float* __restrict__ ls, float* __restrict__ out)
{
    int p = blockIdx.x * blockDim.x + threadIdx.x;
    if (p >= NPIX) return;
    int b  = p >> 14;
    int sp = p & (HWn - 1);
    int y = sp >> 7, x = sp & 127;
    int base = b * Cn * HWn + sp;

    int   yo[3] = { y > 0 ? -Wn : 0, 0, y < Hn-1 ? Wn : 0 };
    int   xo[3] = { x > 0 ? -1  : 0, 0, x < Wn-1 ? 1  : 0 };
    float my[3] = { y > 0 ? 1.f : 0.f, 1.f, y < Hn-1 ? 1.f : 0.f };
    float mx[3] = { x > 0 ? 1.f : 0.f, 1.f, x < Wn-1 ? 1.f : 0.f };
    float mm[9]; int oo[9];
#pragma unroll
    for (int dy = 0; dy < 3; dy++)
#pragma unroll
        for (int dx = 0; dx < 3; dx++) { mm[dy*3+dx] = my[dy]*mx[dx]; oo[dy*3+dx] = yo[dy]+xo[dx]; }

    float acc[64];
#pragma unroll
    for (int k = 0; k < 64; k++) acc[k] = pb1[k];

#pragma unroll 2
    for (int c = 0; c < 64; c++) {
        int cb = base + c*HWn;
        float rv = rdwb[c];
#pragma unroll
        for (int t = 0; t < 9; t++)
            rv += (rdwk[c*9 + t] * mm[t]) * __half2float(outp[cb + oo[t]]);
        const float* __restrict__ wr = pw1T + c*64;
#pragma unroll
        for (int k = 0; k < 64; k++) acc[k] += wr[k] * rv;
    }
#pragma unroll
    for (int k = 0; k < 64; k++) { float v = acc[k]; acc[k] = v > 0.f ? v : 0.2f*v; }

    for (int c = 0; c < 64; c++) {
        float o = pb2[c];
        const float* __restrict__ wr = pw2 + c*64;
#pragma unroll
        for (int j = 0; j < 64; j++) o += wr[j] * acc[j];
        int cb = base + c*HWn;
        out[cb] = __half2float(outp[cb]) + ls[c] * o;
    }
}

extern "C" void kernel_launch(void* const* d_in, const int* in_sizes, int n_in,
                              void* d_out, int out_size, void* d_ws, size_t ws_size,
                              hipStream_t stream)
{
    (void)in_sizes; (void)n_in; (void)out_size; (void)ws_size;
    const float* force   = (const float*)d_in[0];
    const float* style   = (const float*)d_in[1];
    const float* illum   = (const float*)d_in[2];
    const float* h_w1    = (const float*)d_in[3];
    const float* h_b1    = (const float*)d_in[4];
    const float* h_w2    = (const float*)d_in[5];
    const float* h_b2    = (const float*)d_in[6];
    const float* h_w3    = (const float*)d_in[7];
    const float* h_b3    = (const float*)d_in[8];
    const float* dw_k    = (const float*)d_in[9];
    const float* pw_w    = (const float*)d_in[10];
    const float* r_dw_k  = (const float*)d_in[11];
    const float* r_dw_b  = (const float*)d_in[12];
    const float* r_pw1_w = (const float*)d_in[13];
    const float* r_pw1_b = (const float*)d_in[14];
    const float* r_pw2_w = (const float*)d_in[15];
    const float* r_pw2_b = (const float*)d_in[16];
    const float* lscale  = (const float*)d_in[17];

    float* out = (float*)d_out;
    float* Xf  = out + (size_t)NTOT;      // x output region: fp32 ping-pong buffer 0
    float* Vf  = out + 2*(size_t)NTOT;    // v output region: updated in place

    char* w = (char*)d_ws;
    __half* Ah  = (__half*)w; w += (size_t)NTOT*2;
    __half* B2h = (__half*)w; w += (size_t)NTOT*2;
    __half* Gh  = (__half*)w; w += (size_t)NTOT*2;
    __half* Beh = (__half*)w; w += (size_t)NTOT*2;
    __half* X0h = (__half*)w; w += (size_t)NTOT*2;   // fp16 ping-pong buffer 1, reused as out_pre
    float* w1T  = (float*)w;
    float* c1   = w1T + 2048;
    float* pwT  = c1 + 32;
    float* pw1T = pwT + 4096;
    float* mu   = pw1T + 4096;
    float* rs   = mu + 512;

    hipMemsetAsync(Xf, 0, (size_t)NTOT*4, stream);   // x0 = 0
    hipMemsetAsync(Vf, 0, (size_t)NTOT*4, stream);   // v0 = 0

    prep<<<1, 256, 0, stream>>>(style, h_w1, h_b1, pw_w, r_pw1_w, w1T, c1, pwT, pw1T);
    hyper<<<NPIX/256, 256, 0, stream>>>(force, illum, w1T, c1, h_w2, h_b2, h_w3, h_b3,
                                        Ah, B2h, Gh, Beh);
    for (int s = 0; s < 10; s++) {
        if ((s & 1) == 0)
            osc_step<float, __half><<<NPIX/256, 256, 0, stream>>>(Xf, X0h, Vf, force, illum,
                                                                  Ah, B2h, dw_k, pwT);
        else
            osc_step<__half, float><<<NPIX/256, 256, 0, stream>>>(X0h, Xf, Vf, force, illum,
                                                                  Ah, B2h, dw_k, pwT);
    }
    inorm_stats<<<Bn*Cn, 256, 0, stream>>>(force, illum, Xf, mu, rs);
    modulate<<<NTOT/256, 256, 0, stream>>>(force, illum, Xf, Gh, Beh, mu, rs, X0h);
    refine<<<NPIX/256, 256, 0, stream>>>(X0h, r_dw_k, r_dw_b, pw1T, r_pw1_b,
                                         r_pw2_w, r_pw2_b, lscale, out);
}

// Round 2
// 741.255 us; speedup vs baseline: 3.1583x; 3.1583x over previous
//
#include <hip/hip_runtime.h>
#include <hip/hip_fp16.h>

#define Hn 128
#define Wn 128
#define HWn 16384
#define Cn 64
#define Bn 8
#define NTOT (Bn*Cn*HWn)   /* 8388608 */
#define NPIX (Bn*HWn)      /* 131072  */
#define DTc 0.3f
#define EPSc 1e-5f

__device__ __forceinline__ float sigm(float t){ return 1.0f/(1.0f+__expf(-t)); }
__device__ __forceinline__ float ldx(const float* __restrict__ p){ return *p; }
__device__ __forceinline__ float ldx(const __half* __restrict__ p){ return __half2float(*p); }
__device__ __forceinline__ void stx(float* __restrict__ p, float v){ *p = v; }
__device__ __forceinline__ void stx(__half* __restrict__ p, float v){ *p = __float2half(v); }

// ---------------- F = force + 0.2*illum (float4 streaming) ----------------
__global__ void fuseF(const float4* __restrict__ force, const float4* __restrict__ illum,
                      float4* __restrict__ F)
{
    int i = blockIdx.x * blockDim.x + threadIdx.x;      // NTOT/4 threads
    float4 f = force[i], il = illum[i];
    f.x += 0.2f*il.x; f.y += 0.2f*il.y; f.z += 0.2f*il.z; f.w += 0.2f*il.w;
    F[i] = f;
}

// ---------------- prep: style constant + weight transposes ----------------
__global__ void prep(const float* __restrict__ style, const float* __restrict__ w1,
                     const float* __restrict__ b1, const float* __restrict__ pw,
                     const float* __restrict__ pw1, float* __restrict__ w1T,
                     float* __restrict__ c1, float* __restrict__ pwT,
                     float* __restrict__ pw1T)
{
    int t = threadIdx.x;
    if (t < 32) {
        float s = b1[t];
        for (int k = 0; k < 64; k++) s += w1[t*128 + 64 + k] * style[k];
        c1[t] = s;
    }
    for (int i = t; i < 2048; i += 256) { int c = i >> 5, j = i & 31; w1T[i] = w1[j*128 + c]; }
    for (int i = t; i < 4096; i += 256) {
        int c = i >> 6, k = i & 63;
        pwT[i]  = pw[k*64 + c];
        pw1T[i] = pw1[k*64 + c];
    }
}

// ---------------- hyper encoder, 2-way split: y=0 -> AB(half2), y=1 -> GB(half2) --------
__global__ void hyper2(const float* __restrict__ F,
                       const float* __restrict__ w1T, const float* __restrict__ c1,
                       const float* __restrict__ w2, const float* __restrict__ b2,
                       const float* __restrict__ w3, const float* __restrict__ b3,
                       __half2* __restrict__ AB, __half2* __restrict__ GB)
{
    int p = blockIdx.x * blockDim.x + threadIdx.x;
    int b  = p >> 14;
    int sp = p & (HWn - 1);
    int base = b * Cn * HWn + sp;

    float u1[32];
#pragma unroll
    for (int j = 0; j < 32; j++) u1[j] = c1[j];
#pragma unroll 4
    for (int c = 0; c < 64; c++) {
        float fc = F[base + c*HWn];
        const float* __restrict__ wr = w1T + c*32;
#pragma unroll
        for (int j = 0; j < 32; j++) u1[j] += wr[j] * fc;
    }
#pragma unroll
    for (int j = 0; j < 32; j++) { float v = u1[j]; u1[j] = v > 0.f ? v : 0.2f*v; }

    float u2[32];
#pragma unroll
    for (int i = 0; i < 32; i++) {
        float s = b2[i];
#pragma unroll
        for (int j = 0; j < 32; j++) s += w2[i*32 + j] * u1[j];
        u2[i] = s > 0.f ? s : 0.2f*s;
    }

    if (blockIdx.y == 0) {
        for (int j = 0; j < 64; j++) {
            const float* __restrict__ r0 = w3 + j*32;
            const float* __restrict__ r1 = w3 + (64 + j)*32;
            float pwv = b3[j], pz = b3[64 + j];
#pragma unroll
            for (int i = 0; i < 32; i++) { pwv += r0[i]*u2[i]; pz += r1[i]*u2[i]; }
            float om = 2.0f * sigm(pwv);
            float ze = sigm(pz);
            AB[base + j*HWn] = __floats2half2_rn(2.0f * ze * om, om * om);
        }
    } else {
        for (int j = 0; j < 64; j++) {
            const float* __restrict__ r2 = w3 + (128 + j)*32;
            const float* __restrict__ r3 = w3 + (192 + j)*32;
            float pg = b3[128 + j], pb = b3[192 + j];
#pragma unroll
            for (int i = 0; i < 32; i++) { pg += r2[i]*u2[i]; pb += r3[i]*u2[i]; }
            GB[base + j*HWn] = __floats2half2_rn(2.0f * sigm(pg), tanhf(pb));
        }
    }
}

// ---------------- one symplectic-Euler oscillator step, 16-channel split ----------------
template <typename Tin, typename Tout>
__global__ void osc_step(const Tin* __restrict__ Xin, Tout* __restrict__ Xout,
                         float* __restrict__ V, const float* __restrict__ F,
                         const __half2* __restrict__ AB,
                         const float* __restrict__ dwk, const float* __restrict__ pwT)
{
    int p = blockIdx.x * blockDim.x + threadIdx.x;
    int c0 = blockIdx.y << 4;                 // channel group start
    int b  = p >> 14;
    int sp = p & (HWn - 1);
    int y = sp >> 7, x = sp & 127;
    int base = b * Cn * HWn + sp;

    // pointwise coupling: acc[kk] = sum_c pw[c0+kk][c] * x[c]
    float acc[16];
#pragma unroll
    for (int k = 0; k < 16; k++) acc[k] = 0.f;
#pragma unroll 4
    for (int c = 0; c < 64; c++) {
        float xc = ldx(Xin + base + c*HWn);
        const float* __restrict__ wr = pwT + c*64 + c0;
#pragma unroll
        for (int k = 0; k < 16; k++) acc[k] += wr[k] * xc;
    }

    // 3x3 tap masks/offsets (zero 'SAME' padding)
    int   yo[3] = { y > 0 ? -Wn : 0, 0, y < Hn-1 ? Wn : 0 };
    int   xo[3] = { x > 0 ? -1  : 0, 0, x < Wn-1 ? 1  : 0 };
    float my[3] = { y > 0 ? 1.f : 0.f, 1.f, y < Hn-1 ? 1.f : 0.f };
    float mx[3] = { x > 0 ? 1.f : 0.f, 1.f, x < Wn-1 ? 1.f : 0.f };
    float mm[9]; int oo[9];
#pragma unroll
    for (int dy = 0; dy < 3; dy++)
#pragma unroll
        for (int dx = 0; dx < 3; dx++) { mm[dy*3+dx] = my[dy]*mx[dx]; oo[dy*3+dx] = yo[dy]+xo[dx]; }

#pragma unroll
    for (int cc = 0; cc < 16; cc++) {
        int c = c0 + cc;
        int cb = base + c*HWn;
        float tv[9];
#pragma unroll
        for (int t = 0; t < 9; t++) tv[t] = ldx(Xin + cb + oo[t]);
        float dws = 0.f;
#pragma unroll
        for (int t = 0; t < 9; t++) dws += (dwk[c*9 + t] * mm[t]) * tv[t];
        float xc = tv[4];
        float2 ab = __half22float2(AB[cb]);
        float vv = V[cb];
        float accel = F[cb] + acc[cc] + dws - ab.x * vv - ab.y * xc;
        vv += accel * DTc;
        V[cb] = vv;
        stx(Xout + cb, xc + vv * DTc);
    }
}

// ---------------- instance norm stats ----------------
__global__ void inorm_stats(const float* __restrict__ F, const float* __restrict__ X,
                            float* __restrict__ mu, float* __restrict__ rs)
{
    int bc = blockIdx.x;             // 0..511
    int base = bc * HWn;
    float s = 0.f, s2 = 0.f;
    for (int i = threadIdx.x; i < HWn/4; i += blockDim.x) {
        float4 f = *reinterpret_cast<const float4*>(F + base + 4*i);
        float4 xv = *reinterpret_cast<const float4*>(X + base + 4*i);
        float v0 = f.x + xv.x, v1 = f.y + xv.y, v2 = f.z + xv.z, v3 = f.w + xv.w;
        s += (v0 + v1) + (v2 + v3);
        s2 += (v0*v0 + v1*v1) + (v2*v2 + v3*v3);
    }
#pragma unroll
    for (int o = 32; o > 0; o >>= 1) { s += __shfl_down(s, o); s2 += __shfl_down(s2, o); }
    __shared__ float sh[16];
    int w = threadIdx.x >> 6, l = threadIdx.x & 63;
    if (l == 0) { sh[w] = s; sh[8 + w] = s2; }
    __syncthreads();
    if (threadIdx.x == 0) {
        float S = 0.f, S2 = 0.f;
        for (int i = 0; i < 4; i++) { S += sh[i]; S2 += sh[8 + i]; }
        float m = S / (float)HWn;
        float var = S2 / (float)HWn - m*m;
        mu[bc] = m;
        rs[bc] = rsqrtf(var + EPSc);
    }
}

// ---------------- instance norm apply + style modulation -> out_pre (fp16), x4 vectorized ----
__global__ void modulate(const float4* __restrict__ F4, const float4* __restrict__ X4,
                         const __half2* __restrict__ GB, const float* __restrict__ mu,
                         const float* __restrict__ rs, __half* __restrict__ outp)
{
    int e4 = blockIdx.x * blockDim.x + threadIdx.x;   // NTOT/4 threads
    int bc = e4 >> 12;                                // (e4*4) >> 14
    float m = mu[bc], r = rs[bc];
    float4 f = F4[e4], xv = X4[e4];
    uint4 gb = *reinterpret_cast<const uint4*>(GB + 4*(size_t)e4);
    float2 g0 = __half22float2(*(__half2*)&gb.x);
    float2 g1 = __half22float2(*(__half2*)&gb.y);
    float2 g2 = __half22float2(*(__half2*)&gb.z);
    float2 g3 = __half22float2(*(__half2*)&gb.w);
    float o0 = g0.x * ((f.x + xv.x - m) * r) + g0.y;
    float o1 = g1.x * ((f.y + xv.y - m) * r) + g1.y;
    float o2 = g2.x * ((f.z + xv.z - m) * r) + g2.y;
    float o3 = g3.x * ((f.w + xv.w - m) * r) + g3.y;
    __half2 h01 = __floats2half2_rn(o0, o1);
    __half2 h23 = __floats2half2_rn(o2, o3);
    uint2 pack; pack.x = *(unsigned int*)&h01; pack.y = *(unsigned int*)&h23;
    *reinterpret_cast<uint2*>(outp + 4*(size_t)e4) = pack;
}

// ---------------- refine branch, LDS 3-phase: 64 px/block, 4 waves x 16 ch ----------------
__global__ void refine(const __half* __restrict__ outp,
                       const float* __restrict__ rdwk, const float* __restrict__ rdwb,
                       const float* __restrict__ pw1T, const float* __restrict__ pb1,
                       const float* __restrict__ pw2, const float* __restrict__ pb2,
                       const float* __restrict__ ls, float* __restrict__ out)
{
    __shared__ float rv_s[64][64];
    __shared__ float act_s[64][64];
    int l = threadIdx.x & 63;
    int w = threadIdx.x >> 6;
    int p = blockIdx.x * 64 + l;
    int b  = p >> 14;
    int sp = p & (HWn - 1);
    int y = sp >> 7, x = sp & 127;
    int base = b * Cn * HWn + sp;
    int c0 = w << 4;

    int   yo[3] = { y > 0 ? -Wn : 0, 0, y < Hn-1 ? Wn : 0 };
    int   xo[3] = { x > 0 ? -1  : 0, 0, x < Wn-1 ? 1  : 0 };
    float my[3] = { y > 0 ? 1.f : 0.f, 1.f, y < Hn-1 ? 1.f : 0.f };
    float mx[3] = { x > 0 ? 1.f : 0.f, 1.f, x < Wn-1 ? 1.f : 0.f };
    float mm[9]; int oo[9];
#pragma unroll
    for (int dy = 0; dy < 3; dy++)
#pragma unroll
        for (int dx = 0; dx < 3; dx++) { mm[dy*3+dx] = my[dy]*mx[dx]; oo[dy*3+dx] = yo[dy]+xo[dx]; }

    // phase 1: depthwise conv for this wave's 16 channels
#pragma unroll
    for (int cc = 0; cc < 16; cc++) {
        int c = c0 + cc;
        int cb = base + c*HWn;
        float rv = rdwb[c];
#pragma unroll
        for (int t = 0; t < 9; t++)
            rv += (rdwk[c*9 + t] * mm[t]) * __half2float(outp[cb + oo[t]]);
        rv_s[c][l] = rv;
    }
    __syncthreads();

    // phase 2: act[k] = lrelu(pb1[k] + sum_c pw1[k][c]*rv[c])
#pragma unroll 2
    for (int kk = 0; kk < 16; kk++) {
        int k = c0 + kk;
        float a = pb1[k];
#pragma unroll 8
        for (int c = 0; c < 64; c++) a += pw1T[c*64 + k] * rv_s[c][l];
        act_s[k][l] = a > 0.f ? a : 0.2f*a;
    }
    __syncthreads();

    // phase 3: out = outp + ls * (pb2 + pw2 @ act)
#pragma unroll 2
    for (int cc = 0; cc < 16; cc++) {
        int c = c0 + cc;
        float o = pb2[c];
#pragma unroll 8
        for (int j = 0; j < 64; j++) o += pw2[c*64 + j] * act_s[j][l];
        int cb = base + c*HWn;
        out[cb] = __half2float(outp[cb]) + ls[c] * o;
    }
}

extern "C" void kernel_launch(void* const* d_in, const int* in_sizes, int n_in,
                              void* d_out, int out_size, void* d_ws, size_t ws_size,
                              hipStream_t stream)
{
    (void)in_sizes; (void)n_in; (void)out_size; (void)ws_size;
    const float* force   = (const float*)d_in[0];
    const float* style   = (const float*)d_in[1];
    const float* illum   = (const float*)d_in[2];
    const float* h_w1    = (const float*)d_in[3];
    const float* h_b1    = (const float*)d_in[4];
    const float* h_w2    = (const float*)d_in[5];
    const float* h_b2    = (const float*)d_in[6];
    const float* h_w3    = (const float*)d_in[7];
    const float* h_b3    = (const float*)d_in[8];
    const float* dw_k    = (const float*)d_in[9];
    const float* pw_w    = (const float*)d_in[10];
    const float* r_dw_k  = (const float*)d_in[11];
    const float* r_dw_b  = (const float*)d_in[12];
    const float* r_pw1_w = (const float*)d_in[13];
    const float* r_pw1_b = (const float*)d_in[14];
    const float* r_pw2_w = (const float*)d_in[15];
    const float* r_pw2_b = (const float*)d_in[16];
    const float* lscale  = (const float*)d_in[17];

    float* out = (float*)d_out;
    float* Ff  = out;                     // out region doubles as F until refine
    float* Xf  = out + (size_t)NTOT;      // x output region: fp32 ping-pong buffer 0
    float* Vf  = out + 2*(size_t)NTOT;    // v output region: updated in place

    char* w = (char*)d_ws;
    __half2* AB = (__half2*)w; w += (size_t)NTOT*4;
    __half2* GB = (__half2*)w; w += (size_t)NTOT*4;
    __half*  X0h = (__half*)w; w += (size_t)NTOT*2;   // fp16 ping-pong buffer 1, reused as out_pre
    float* w1T  = (float*)w;
    float* c1   = w1T + 2048;
    float* pwT  = c1 + 32;
    float* pw1T = pwT + 4096;
    float* mu   = pw1T + 4096;
    float* rs   = mu + 512;

    hipMemsetAsync(Xf, 0, (size_t)NTOT*4, stream);   // x0 = 0
    hipMemsetAsync(Vf, 0, (size_t)NTOT*4, stream);   // v0 = 0

    fuseF<<<NTOT/1024, 256, 0, stream>>>((const float4*)force, (const float4*)illum,
                                         (float4*)Ff);
    prep<<<1, 256, 0, stream>>>(style, h_w1, h_b1, pw_w, r_pw1_w, w1T, c1, pwT, pw1T);
    hyper2<<<dim3(NPIX/256, 2), 256, 0, stream>>>(Ff, w1T, c1, h_w2, h_b2, h_w3, h_b3,
                                                  AB, GB);
    for (int s = 0; s < 10; s++) {
        if ((s & 1) == 0)
            osc_step<float, __half><<<dim3(NPIX/256, 4), 256, 0, stream>>>(Xf, X0h, Vf, Ff,
                                                                           AB, dw_k, pwT);
        else
            osc_step<__half, float><<<dim3(NPIX/256, 4), 256, 0, stream>>>(X0h, Xf, Vf, Ff,
                                                                           AB, dw_k, pwT);
    }
    inorm_stats<<<Bn*Cn, 256, 0, stream>>>(Ff, Xf, mu, rs);
    modulate<<<NTOT/1024, 256, 0, stream>>>((const float4*)Ff, (const float4*)Xf,
                                            GB, mu, rs, X0h);
    refine<<<NPIX/64, 256, 0, stream>>>(X0h, r_dw_k, r_dw_b, pw1T, r_pw1_b,
                                        r_pw2_w, r_pw2_b, lscale, out);
}

// Round 5
// 590.069 us; speedup vs baseline: 3.9675x; 1.2562x over previous
//
#include <hip/hip_runtime.h>
#include <hip/hip_fp16.h>

#define Hn 128
#define Wn 128
#define HWn 16384
#define Cn 64
#define Bn 8
#define NTOT (Bn*Cn*HWn)   /* 8388608 */
#define NPIX (Bn*HWn)      /* 131072  */
#define DTc 0.3f
#define EPSc 1e-5f

__device__ __forceinline__ float sigm(float t){ return 1.0f/(1.0f+__expf(-t)); }

// ---------------- F = force + 0.2*illum (fp16) + fused oscillator step 0 ----------------
// x0=v0=0  =>  accel0 = F, v1 = 0.3*F, x1 = 0.09*F
__global__ void fuseF0(const float4* __restrict__ force, const float4* __restrict__ illum,
                       __half* __restrict__ F, __half* __restrict__ XA, __half* __restrict__ V)
{
    int i = blockIdx.x * blockDim.x + threadIdx.x;      // NTOT/4 threads
    float4 f = force[i], il = illum[i];
    float a0 = f.x + 0.2f*il.x, a1 = f.y + 0.2f*il.y;
    float a2 = f.z + 0.2f*il.z, a3 = f.w + 0.2f*il.w;
    uint2 pf, px, pv;
    __half2 h;
    h = __floats2half2_rn(a0, a1);            pf.x = *(unsigned int*)&h;
    h = __floats2half2_rn(a2, a3);            pf.y = *(unsigned int*)&h;
    h = __floats2half2_rn(0.09f*a0, 0.09f*a1); px.x = *(unsigned int*)&h;
    h = __floats2half2_rn(0.09f*a2, 0.09f*a3); px.y = *(unsigned int*)&h;
    h = __floats2half2_rn(0.3f*a0, 0.3f*a1);   pv.x = *(unsigned int*)&h;
    h = __floats2half2_rn(0.3f*a2, 0.3f*a3);   pv.y = *(unsigned int*)&h;
    *reinterpret_cast<uint2*>(F  + 4*(size_t)i) = pf;
    *reinterpret_cast<uint2*>(XA + 4*(size_t)i) = px;
    *reinterpret_cast<uint2*>(V  + 4*(size_t)i) = pv;
}

// ---------------- prep: style constant + weight transposes ----------------
__global__ void prep(const float* __restrict__ style, const float* __restrict__ w1,
                     const float* __restrict__ b1, const float* __restrict__ pw,
                     const float* __restrict__ pw1, const float* __restrict__ pw2,
                     float* __restrict__ w1T, float* __restrict__ c1,
                     float* __restrict__ pwT, float* __restrict__ pw1T,
                     float* __restrict__ pw2T)
{
    int t = threadIdx.x;
    if (t < 32) {
        float s = b1[t];
        for (int k = 0; k < 64; k++) s += w1[t*128 + 64 + k] * style[k];
        c1[t] = s;
    }
    for (int i = t; i < 2048; i += 256) { int c = i >> 5, j = i & 31; w1T[i] = w1[j*128 + c]; }
    for (int i = t; i < 4096; i += 256) {
        int c = i >> 6, k = i & 63;
        pwT[i]  = pw[k*64 + c];
        pw1T[i] = pw1[k*64 + c];
        pw2T[i] = pw2[k*64 + c];
    }
}

// ---------------- hyper encoder, 2-way split: y=0 -> AB(half2), y=1 -> GB(half2) --------
__global__ void hyper2(const __half* __restrict__ F,
                       const float* __restrict__ w1T, const float* __restrict__ c1,
                       const float* __restrict__ w2, const float* __restrict__ b2,
                       const float* __restrict__ w3, const float* __restrict__ b3,
                       __half2* __restrict__ AB, __half2* __restrict__ GB)
{
    int p = blockIdx.x * blockDim.x + threadIdx.x;
    int b  = p >> 14;
    int sp = p & (HWn - 1);
    int base = b * Cn * HWn + sp;

    float u1[32];
#pragma unroll
    for (int j = 0; j < 32; j++) u1[j] = c1[j];
#pragma unroll 4
    for (int c = 0; c < 64; c++) {
        float fc = __half2float(F[base + c*HWn]);
        const float* __restrict__ wr = w1T + c*32;
#pragma unroll
        for (int j = 0; j < 32; j++) u1[j] += wr[j] * fc;
    }
#pragma unroll
    for (int j = 0; j < 32; j++) { float v = u1[j]; u1[j] = v > 0.f ? v : 0.2f*v; }

    float u2[32];
#pragma unroll
    for (int i = 0; i < 32; i++) {
        float s = b2[i];
#pragma unroll
        for (int j = 0; j < 32; j++) s += w2[i*32 + j] * u1[j];
        u2[i] = s > 0.f ? s : 0.2f*s;
    }

    if (blockIdx.y == 0) {
        for (int j = 0; j < 64; j++) {
            const float* __restrict__ r0 = w3 + j*32;
            const float* __restrict__ r1 = w3 + (64 + j)*32;
            float pwv = b3[j], pz = b3[64 + j];
#pragma unroll
            for (int i = 0; i < 32; i++) { pwv += r0[i]*u2[i]; pz += r1[i]*u2[i]; }
            float om = 2.0f * sigm(pwv);
            float ze = sigm(pz);
            AB[base + j*HWn] = __floats2half2_rn(2.0f * ze * om, om * om);
        }
    } else {
        for (int j = 0; j < 64; j++) {
            const float* __restrict__ r2 = w3 + (128 + j)*32;
            const float* __restrict__ r3 = w3 + (192 + j)*32;
            float pg = b3[128 + j], pb = b3[192 + j];
#pragma unroll
            for (int i = 0; i < 32; i++) { pg += r2[i]*u2[i]; pb += r3[i]*u2[i]; }
            GB[base + j*HWn] = __floats2half2_rn(2.0f * sigm(pg), tanhf(pb));
        }
    }
}

// ---------------- one symplectic-Euler oscillator step, 16-channel split, fp16 state ------
template <typename Tout>
__global__ void osc_step(const __half* __restrict__ Xin, Tout* __restrict__ Xout,
                         __half* __restrict__ V, const __half* __restrict__ F,
                         const __half2* __restrict__ AB,
                         const float* __restrict__ dwk, const float* __restrict__ pwT)
{
    int p = blockIdx.x * blockDim.x + threadIdx.x;
    int c0 = blockIdx.y << 4;                 // channel group start
    int b  = p >> 14;
    int sp = p & (HWn - 1);
    int y = sp >> 7, x = sp & 127;
    int base = b * Cn * HWn + sp;

    // pointwise coupling: acc[kk] = sum_c pw[c0+kk][c] * x[c]
    float acc[16];
#pragma unroll
    for (int k = 0; k < 16; k++) acc[k] = 0.f;
#pragma unroll 4
    for (int c = 0; c < 64; c++) {
        float xc = __half2float(Xin[base + c*HWn]);
        const float* __restrict__ wr = pwT + c*64 + c0;
#pragma unroll
        for (int k = 0; k < 16; k++) acc[k] += wr[k] * xc;
    }

    // 3x3 tap masks/offsets (zero 'SAME' padding)
    int   yo[3] = { y > 0 ? -Wn : 0, 0, y < Hn-1 ? Wn : 0 };
    int   xo[3] = { x > 0 ? -1  : 0, 0, x < Wn-1 ? 1  : 0 };
    float my[3] = { y > 0 ? 1.f : 0.f, 1.f, y < Hn-1 ? 1.f : 0.f };
    float mx[3] = { x > 0 ? 1.f : 0.f, 1.f, x < Wn-1 ? 1.f : 0.f };
    float mm[9]; int oo[9];
#pragma unroll
    for (int dy = 0; dy < 3; dy++)
#pragma unroll
        for (int dx = 0; dx < 3; dx++) { mm[dy*3+dx] = my[dy]*mx[dx]; oo[dy*3+dx] = yo[dy]+xo[dx]; }

#pragma unroll
    for (int cc = 0; cc < 16; cc++) {
        int c = c0 + cc;
        int cb = base + c*HWn;
        float tv[9];
#pragma unroll
        for (int t = 0; t < 9; t++) tv[t] = __half2float(Xin[cb + oo[t]]);
        float dws = 0.f;
#pragma unroll
        for (int t = 0; t < 9; t++) dws += (dwk[c*9 + t] * mm[t]) * tv[t];
        float xc = tv[4];
        float2 ab = __half22float2(AB[cb]);
        float vv = __half2float(V[cb]);
        float accel = __half2float(F[cb]) + acc[cc] + dws - ab.x * vv - ab.y * xc;
        vv += accel * DTc;
        V[cb] = __float2half(vv);
        float xn = xc + vv * DTc;
        if constexpr (sizeof(Tout) == 4) Xout[cb] = xn;
        else                             Xout[cb] = __float2half(xn);
    }
}

// ---------------- V fp16 -> fp32 into d_out v region ----------------
__global__ void vconvert(const __half* __restrict__ Vh, float4* __restrict__ Vf)
{
    int i = blockIdx.x * blockDim.x + threadIdx.x;      // NTOT/4
    uint2 u = *reinterpret_cast<const uint2*>(Vh + 4*(size_t)i);
    float2 a = __half22float2(*(__half2*)&u.x);
    float2 b = __half22float2(*(__half2*)&u.y);
    Vf[i] = make_float4(a.x, a.y, b.x, b.y);
}

// ---------------- instance norm stats ----------------
__global__ void inorm_stats(const __half* __restrict__ F, const float* __restrict__ X,
                            float* __restrict__ mu, float* __restrict__ rs)
{
    int bc = blockIdx.x;             // 0..511
    int base = bc * HWn;
    const __half2* __restrict__ F2 = (const __half2*)(F + base);
    const float4*  __restrict__ X4 = (const float4*)(X + base);
    float s = 0.f, s2 = 0.f;
    for (int i = threadIdx.x; i < HWn/4; i += blockDim.x) {
        float4 xv = X4[i];
        float2 f0 = __half22float2(F2[2*i]);
        float2 f1 = __half22float2(F2[2*i+1]);
        float v0 = f0.x + xv.x, v1 = f0.y + xv.y, v2 = f1.x + xv.z, v3 = f1.y + xv.w;
        s += (v0 + v1) + (v2 + v3);
        s2 += (v0*v0 + v1*v1) + (v2*v2 + v3*v3);
    }
#pragma unroll
    for (int o = 32; o > 0; o >>= 1) { s += __shfl_down(s, o); s2 += __shfl_down(s2, o); }
    __shared__ float sh[16];
    int w = threadIdx.x >> 6, l = threadIdx.x & 63;
    if (l == 0) { sh[w] = s; sh[8 + w] = s2; }
    __syncthreads();
    if (threadIdx.x == 0) {
        float S = 0.f, S2 = 0.f;
        for (int i = 0; i < 4; i++) { S += sh[i]; S2 += sh[8 + i]; }
        float m = S / (float)HWn;
        float var = S2 / (float)HWn - m*m;
        mu[bc] = m;
        rs[bc] = rsqrtf(var + EPSc);
    }
}

// ---------------- instance norm apply + style modulation -> out_pre (fp16), x4 vectorized ----
__global__ void modulate(const __half* __restrict__ F, const float4* __restrict__ X4,
                         const uint4* __restrict__ GBu, const float* __restrict__ mu,
                         const float* __restrict__ rs, __half* __restrict__ outp)
{
    int e4 = blockIdx.x * blockDim.x + threadIdx.x;   // NTOT/4 threads
    int bc = e4 >> 12;                                // (e4*4) >> 14
    float m = mu[bc], r = rs[bc];
    uint2 fu = *reinterpret_cast<const uint2*>(F + 4*(size_t)e4);
    float2 f0 = __half22float2(*(__half2*)&fu.x);
    float2 f1 = __half22float2(*(__half2*)&fu.y);
    float4 xv = X4[e4];
    uint4 gb = GBu[e4];
    float2 g0 = __half22float2(*(__half2*)&gb.x);
    float2 g1 = __half22float2(*(__half2*)&gb.y);
    float2 g2 = __half22float2(*(__half2*)&gb.z);
    float2 g3 = __half22float2(*(__half2*)&gb.w);
    float o0 = g0.x * ((f0.x + xv.x - m) * r) + g0.y;
    float o1 = g1.x * ((f0.y + xv.y - m) * r) + g1.y;
    float o2 = g2.x * ((f1.x + xv.z - m) * r) + g2.y;
    float o3 = g3.x * ((f1.y + xv.w - m) * r) + g3.y;
    __half2 h01 = __floats2half2_rn(o0, o1);
    __half2 h23 = __floats2half2_rn(o2, o3);
    uint2 pack; pack.x = *(unsigned int*)&h01; pack.y = *(unsigned int*)&h23;
    *reinterpret_cast<uint2*>(outp + 4*(size_t)e4) = pack;
}

// ---------------- refine branch, LDS 3-phase, loop-swapped register accumulation ----------
__global__ void refine(const __half* __restrict__ outp,
                       const float* __restrict__ rdwk, const float* __restrict__ rdwb,
                       const float* __restrict__ pw1T, const float* __restrict__ pb1,
                       const float* __restrict__ pw2T, const float* __restrict__ pb2,
                       const float* __restrict__ ls, float* __restrict__ out)
{
    __shared__ float rv_s[64][64];
    __shared__ float act_s[64][64];
    int l = threadIdx.x & 63;
    int w = threadIdx.x >> 6;
    int p = blockIdx.x * 64 + l;
    int b  = p >> 14;
    int sp = p & (HWn - 1);
    int y = sp >> 7, x = sp & 127;
    int base = b * Cn * HWn + sp;
    int c0 = w << 4;

    int   yo[3] = { y > 0 ? -Wn : 0, 0, y < Hn-1 ? Wn : 0 };
    int   xo[3] = { x > 0 ? -1  : 0, 0, x < Wn-1 ? 1  : 0 };
    float my[3] = { y > 0 ? 1.f : 0.f, 1.f, y < Hn-1 ? 1.f : 0.f };
    float mx[3] = { x > 0 ? 1.f : 0.f, 1.f, x < Wn-1 ? 1.f : 0.f };
    float mm[9]; int oo[9];
#pragma unroll
    for (int dy = 0; dy < 3; dy++)
#pragma unroll
        for (int dx = 0; dx < 3; dx++) { mm[dy*3+dx] = my[dy]*mx[dx]; oo[dy*3+dx] = yo[dy]+xo[dx]; }

    // phase 1: depthwise conv for this wave's 16 channels
#pragma unroll
    for (int cc = 0; cc < 16; cc++) {
        int c = c0 + cc;
        int cb = base + c*HWn;
        float rv = rdwb[c];
#pragma unroll
        for (int t = 0; t < 9; t++)
            rv += (rdwk[c*9 + t] * mm[t]) * __half2float(outp[cb + oo[t]]);
        rv_s[c][l] = rv;
    }
    __syncthreads();

    // phase 2: act[k] = lrelu(pb1[k] + sum_c pw1[k][c]*rv[c]) — one LDS read per c
    float acc[16];
#pragma unroll
    for (int kk = 0; kk < 16; kk++) acc[kk] = pb1[c0 + kk];
#pragma unroll 4
    for (int c = 0; c < 64; c++) {
        float rv = rv_s[c][l];
        const float* __restrict__ wr = pw1T + c*64 + c0;
#pragma unroll
        for (int kk = 0; kk < 16; kk++) acc[kk] += wr[kk] * rv;
    }
#pragma unroll
    for (int kk = 0; kk < 16; kk++) {
        float a = acc[kk];
        act_s[c0 + kk][l] = a > 0.f ? a : 0.2f*a;
    }
    __syncthreads();

    // phase 3: out = outp + ls * (pb2 + pw2 @ act) — one LDS read per j
#pragma unroll
    for (int cc = 0; cc < 16; cc++) acc[cc] = pb2[c0 + cc];
#pragma unroll 4
    for (int j = 0; j < 64; j++) {
        float a = act_s[j][l];
        const float* __restrict__ wr = pw2T + j*64 + c0;
#pragma unroll
        for (int cc = 0; cc < 16; cc++) acc[cc] += wr[cc] * a;
    }
#pragma unroll
    for (int cc = 0; cc < 16; cc++) {
        int c = c0 + cc;
        int cb = base + c*HWn;
        out[cb] = __half2float(outp[cb]) + ls[c] * acc[cc];
    }
}

extern "C" void kernel_launch(void* const* d_in, const int* in_sizes, int n_in,
                              void* d_out, int out_size, void* d_ws, size_t ws_size,
                              hipStream_t stream)
{
    (void)in_sizes; (void)n_in; (void)out_size; (void)ws_size;
    const float* force   = (const float*)d_in[0];
    const float* style   = (const float*)d_in[1];
    const float* illum   = (const float*)d_in[2];
    const float* h_w1    = (const float*)d_in[3];
    const float* h_b1    = (const float*)d_in[4];
    const float* h_w2    = (const float*)d_in[5];
    const float* h_b2    = (const float*)d_in[6];
    const float* h_w3    = (const float*)d_in[7];
    const float* h_b3    = (const float*)d_in[8];
    const float* dw_k    = (const float*)d_in[9];
    const float* pw_w    = (const float*)d_in[10];
    const float* r_dw_k  = (const float*)d_in[11];
    const float* r_dw_b  = (const float*)d_in[12];
    const float* r_pw1_w = (const float*)d_in[13];
    const float* r_pw1_b = (const float*)d_in[14];
    const float* r_pw2_w = (const float*)d_in[15];
    const float* r_pw2_b = (const float*)d_in[16];
    const float* lscale  = (const float*)d_in[17];

    float* out  = (float*)d_out;              // holds GB (half2) until refine overwrites
    float* Xf32 = out + (size_t)NTOT;         // final x fp32 (free until step 9)
    float* Vf32 = out + 2*(size_t)NTOT;       // X fp16 ping-pong during steps; final v fp32
    __half*  XA = (__half*)Vf32;
    __half*  XB = XA + (size_t)NTOT;
    __half2* GB = (__half2*)out;

    char* w = (char*)d_ws;
    __half2* AB = (__half2*)w; w += (size_t)NTOT*4;
    __half*  F  = (__half*)w;  w += (size_t)NTOT*2;
    __half*  Vh = (__half*)w;  w += (size_t)NTOT*2;
    float* w1T  = (float*)w;
    float* c1   = w1T + 2048;
    float* pwT  = c1 + 32;
    float* pw1T = pwT + 4096;
    float* pw2T = pw1T + 4096;
    float* mu   = pw2T + 4096;
    float* rs   = mu + 512;
    __half* outp = (__half*)AB;               // AB dead after last osc step

    fuseF0<<<NTOT/1024, 256, 0, stream>>>((const float4*)force, (const float4*)illum,
                                          F, XA, Vh);
    prep<<<1, 256, 0, stream>>>(style, h_w1, h_b1, pw_w, r_pw1_w, r_pw2_w,
                                w1T, c1, pwT, pw1T, pw2T);
    hyper2<<<dim3(NPIX/256, 2), 256, 0, stream>>>(F, w1T, c1, h_w2, h_b2, h_w3, h_b3,
                                                  AB, GB);
    for (int s = 1; s <= 8; s++) {
        const __half* xin = (s & 1) ? XA : XB;
        __half*      xout = (s & 1) ? XB : XA;
        osc_step<__half><<<dim3(NPIX/256, 4), 256, 0, stream>>>(xin, xout, Vh, F,
                                                                AB, dw_k, pwT);
    }
    // step 9 (odd): reads XA, writes fp32 x directly to d_out
    osc_step<float><<<dim3(NPIX/256, 4), 256, 0, stream>>>(XA, Xf32, Vh, F,
                                                           AB, dw_k, pwT);
    vconvert<<<NTOT/1024, 256, 0, stream>>>(Vh, (float4*)Vf32);
    inorm_stats<<<Bn*Cn, 256, 0, stream>>>(F, Xf32, mu, rs);
    modulate<<<NTOT/1024, 256, 0, stream>>>(F, (const float4*)Xf32,
                                            (const uint4*)GB, mu, rs, outp);
    refine<<<NPIX/64, 256, 0, stream>>>(outp, r_dw_k, r_dw_b, pw1T, r_pw1_b,
                                        pw2T, r_pw2_b, lscale, out);
}